// Round 18
// baseline (647.437 us; speedup 1.0000x reference)
//
#include <hip/hip_runtime.h>
#include <hip/hip_bf16.h>

// Problem constants
#define NB    2048   // batch
#define SS    200    // seq len
#define NTIL  13     // s-tiles of 16 (208 padded)
#define DSEQ  256
#define DITEM 64
#define AA    128    // attn dim (H=1, HD=128)

typedef __bf16 bf16x8 __attribute__((ext_vector_type(8)));
typedef float  f32x4  __attribute__((ext_vector_type(4)));

__device__ __forceinline__ float prelu_f(float x, float a) { return x >= 0.f ? x : a * x; }

// 16-lane reduce via DPP row_ror — VALU pipe only; result valid in all 16 lanes.
#define ROR_F(x, n) __int_as_float(__builtin_amdgcn_update_dpp(0, __float_as_int(x), 0x120 + (n), 0xf, 0xf, true))
__device__ __forceinline__ float row_sum16(float x) {
    x += ROR_F(x, 1); x += ROR_F(x, 2); x += ROR_F(x, 4); x += ROR_F(x, 8);
    return x;
}
__device__ __forceinline__ float row_max16(float x) {
    x = fmaxf(x, ROR_F(x, 1)); x = fmaxf(x, ROR_F(x, 2));
    x = fmaxf(x, ROR_F(x, 4)); x = fmaxf(x, ROR_F(x, 8));
    return x;
}

// ---------------- prep: W_k|W_v -> bf16 [256 rows][512B], XOR-swizzled within rows
// element (a,d) stored at byte (d*2) ^ ((a&7)<<4) of row a
__global__ void prep_kernel(const float* __restrict__ Wk, const float* __restrict__ Wv,
                            __hip_bfloat16* __restrict__ Wb) {
    int idx = blockIdx.x * 256 + threadIdx.x;   // 256 blocks -> 65536
    int a = idx >> 8, d = idx & 255;
    float v = (a < 128) ? Wk[a * 256 + d] : Wv[(a - 128) * 256 + d];
    int boff = (d * 2) ^ ((a & 7) << 4);
    Wb[a * 256 + (boff >> 1)] = __float2bfloat16(v);
}

// per-thread staging: thread handles row srow, 32B chunk `chunk` of the 16x256 f32 tile
#define ISSUE(tt)                                                               \
    {                                                                           \
        int r_ = (tt) * 16 + srow; r_ = r_ < SS ? r_ : SS - 1;                  \
        const float* xp_ = X + ((size_t)b * SS + r_) * DSEQ + chunk * 8;        \
        stlo = *reinterpret_cast<const f32x4*>(xp_);                            \
        sthi = *reinterpret_cast<const f32x4*>(xp_ + 4);                        \
    }

#define STAGE(buf)                                                              \
    {                                                                           \
        bf16x8 v_;                                                              \
        v_[0] = (__bf16)stlo[0]; v_[1] = (__bf16)stlo[1];                       \
        v_[2] = (__bf16)stlo[2]; v_[3] = (__bf16)stlo[3];                       \
        v_[4] = (__bf16)sthi[0]; v_[5] = (__bf16)sthi[1];                       \
        v_[6] = (__bf16)sthi[2]; v_[7] = (__bf16)sthi[3];                       \
        *reinterpret_cast<bf16x8*>(xbase + (buf) * 8192 + wr_off) = v_;         \
    }

// deferred online-softmax + V-fold of tile `tp` (scores of tp are in sp[tp&1])
#define SMFOLD(tp)                                                              \
    {                                                                           \
        const int q_ = (tp) & 1;                                                \
        const int s0_ = (tp) * 16;                                              \
        f32x4 r0_ = *reinterpret_cast<const f32x4*>(&sp[q_][c][0]);             \
        f32x4 r1_ = *reinterpret_cast<const f32x4*>(&sp[q_][c][4]);             \
        float sc_ = (r0_[0]+r0_[1]+r0_[2]+r0_[3]+r1_[0]+r1_[1]+r1_[2]+r1_[3]) * inv_scale; \
        sc_ = mask_lds[s0_ + c] ? -1e9f : sc_;                                  \
        if (tid < 16) score_buf[s0_ + tid] = sc_;                               \
        float tmax_ = row_max16(sc_);                                           \
        float nm_ = fmaxf(m, tmax_);                                            \
        float fs_ = __expf(m - nm_);                                            \
        float e_  = __expf(sc_ - nm_);                                          \
        float ls_ = row_sum16(e_);                                              \
        l = l * fs_ + ls_; m = nm_;                                             \
        oacc *= fs_;                                                            \
        _Pragma("unroll")                                                       \
        for (int i_ = 0; i_ < 4; i_++) {                                        \
            float ew_ = __shfl(e_, (lane & 48) | (rg * 4 + i_), 64);            \
            oacc += ew_ * prelu_f(aVp[i_], pa);                                 \
        }                                                                       \
    }

// ---------------- main: one BLOCK (8 waves) per batch row; cooperative LDS staging.
// ZERO weight registers: both K and V fragments streamed from L2 (Wb is 128 KB,
// chip-shared). Target: 64-VGPR tier -> 8 waves/SIMD, 4 blocks/CU resident.
__global__ __launch_bounds__(512, 8)
void pool_main(
    const float* __restrict__ X,      // [2048,200,256]
    const int*   __restrict__ maskp,  // [2048,200] 1 = pad
    const float* __restrict__ temb,   // [2048,64]
    const float* __restrict__ Wq,     // [128,64]
    const float* __restrict__ Wker,   // [128,128]
    const float* __restrict__ ffnW,   // [256,128]
    const float* __restrict__ ffnb,   // [256]
    const float* __restrict__ prelu_a,
    const __hip_bfloat16* __restrict__ Wb,  // ws: swizzled bf16 weights [256][256]
    float* __restrict__ out)          // [2048*256] ffn, then [2048*200] attn
{
    __shared__ __hip_bfloat16 Xt[2][16][256];    // 16 KB, dbuf bf16 X tile (swizzled)
    __shared__ float sp[2][16][8];               // [par][s][wave] score partials
    __shared__ float score_buf[208];
    __shared__ float out_vec[AA];
    __shared__ float tq[DITEM];
    __shared__ float Qv[AA];
    __shared__ float uv[AA];
    __shared__ int   mask_lds[208];

    const int tid  = threadIdx.x;
    const int w    = tid >> 6;        // wave 0..7
    const int lane = tid & 63;
    const int c    = lane & 15;       // D col (a within wave's 16) / s in tile
    const int rg   = lane >> 4;       // k-group / D-row-group
    const int b    = blockIdx.x;
    const float pa = *prelu_a;
    const float inv_scale = 0.08838834764831845f;  // 1/sqrt(128)

    const int srow  = tid >> 5;       // staging row 0..15
    const int chunk = tid & 31;       // 32B chunk in row
    const int wr_off = srow * 512 + ((chunk * 16) ^ ((srow & 7) << 4));
    char* xbase = (char*)&Xt[0][0][0];
    const int rswz = (c & 7) << 4;

    // weight fragment base pointers (L2-resident, shared chip-wide)
    const char* kb = (const char*)Wb + (size_t)(16 * w + c) * 512;
    const char* vb = kb + 65536;

    // ---- small staging + X tile-0 issue
    if (tid < DITEM) tq[tid] = temb[(size_t)b * DITEM + tid];
    if (tid < 208)   mask_lds[tid] = (tid < SS) ? maskp[(size_t)b * SS + tid] : 1;
    f32x4 stlo, sthi;
    ISSUE(0);
    __syncthreads();

    // ---- Q = prelu(W_q @ t)
    if (tid < AA) {
        float acc = 0.f;
        #pragma unroll
        for (int d4 = 0; d4 < 16; d4++) {
            f32x4 tv = *reinterpret_cast<const f32x4*>(&tq[d4 * 4]);
            f32x4 wq4 = *reinterpret_cast<const f32x4*>(Wq + (size_t)tid * DITEM + d4 * 4);
            acc += wq4[0]*tv[0] + wq4[1]*tv[1] + wq4[2]*tv[2] + wq4[3]*tv[3];
        }
        Qv[tid] = prelu_f(acc, pa);
    }
    __syncthreads();

    // ---- u = W_kernel @ Q
    if (tid < AA) {
        float acc = 0.f;
        #pragma unroll
        for (int d4 = 0; d4 < 32; d4++) {
            f32x4 qv = *reinterpret_cast<const f32x4*>(&Qv[d4 * 4]);
            f32x4 wv4 = *reinterpret_cast<const f32x4*>(Wker + (size_t)tid * AA + d4 * 4);
            acc += wv4[0]*qv[0] + wv4[1]*qv[1] + wv4[2]*qv[2] + wv4[3]*qv[3];
        }
        uv[tid] = acc;
    }
    __syncthreads();
    const float uwK = uv[16 * w + c];

    // tile 0 -> LDS
    STAGE(0);
    __syncthreads();

    // ---- main loop: 1 barrier per tile, deferred softmax, zero weight regs
    float m = -INFINITY, l = 0.f, oacc = 0.f;
    f32x4 aVp = {0.f, 0.f, 0.f, 0.f};

    for (int t = 0; t < NTIL; t++) {
        if (t + 1 < NTIL) ISSUE(t + 1);

        const char* rb = xbase + (t & 1) * 8192 + c * 512;

        // deferred softmax + V-fold of tile t-1
        if (t > 0) SMFOLD(t - 1);

        // K/V MFMA: af from LDS, K/V frags from L2, all consumed immediately
        f32x4 aK = {0.f, 0.f, 0.f, 0.f};
        f32x4 aV = {0.f, 0.f, 0.f, 0.f};
        #pragma unroll
        for (int k = 0; k < 8; k++) {
            const int o = (k * 64 + rg * 16) ^ rswz;
            bf16x8 af = *reinterpret_cast<const bf16x8*>(rb + o);
            bf16x8 bk = *reinterpret_cast<const bf16x8*>(kb + o);   // L2 hit
            bf16x8 bv = *reinterpret_cast<const bf16x8*>(vb + o);   // L2 hit
            aK = __builtin_amdgcn_mfma_f32_16x16x32_bf16(af, bk, aK, 0, 0, 0);
            aV = __builtin_amdgcn_mfma_f32_16x16x32_bf16(af, bv, aV, 0, 0, 0);
        }
        float pr[4];
        #pragma unroll
        for (int i = 0; i < 4; i++) pr[i] = row_sum16(prelu_f(aK[i], pa) * uwK);
        if (c == 0) {
            #pragma unroll
            for (int i = 0; i < 4; i++) sp[t & 1][rg * 4 + i][w] = pr[i];
        }
        aVp = aV;

        // stage tile t+1 into the other buffer
        if (t + 1 < NTIL) STAGE((t + 1) & 1);
        __syncthreads();
    }

    // ---- epilogue: fold last tile, reduce, outputs
    SMFOLD(NTIL - 1);
    oacc += __shfl_xor(oacc, 16, 64);
    oacc += __shfl_xor(oacc, 32, 64);
    const float invl = 1.0f / l;
    if (lane < 16) out_vec[16 * w + lane] = oacc * invl;
    __syncthreads();

    // attn output [b][200]
    if (tid < SS)
        out[(size_t)NB * DSEQ + (size_t)b * SS + tid] = __expf(score_buf[tid] - m) * invl;

    // FFN: out[o] = prelu(b[o] + sum_a ov[a]*ffnW[o][a])
    if (tid < DSEQ) {
        float acc = ffnb[tid];
        #pragma unroll 8
        for (int a4 = 0; a4 < 32; a4++) {
            f32x4 ov = *reinterpret_cast<const f32x4*>(&out_vec[a4 * 4]);
            f32x4 wv4 = *reinterpret_cast<const f32x4*>(ffnW + (size_t)tid * AA + a4 * 4);
            acc += wv4[0]*ov[0] + wv4[1]*ov[1] + wv4[2]*ov[2] + wv4[3]*ov[3];
        }
        out[(size_t)b * DSEQ + tid] = prelu_f(acc, pa);
    }
}

extern "C" void kernel_launch(void* const* d_in, const int* in_sizes, int n_in,
                              void* d_out, int out_size, void* d_ws, size_t ws_size,
                              hipStream_t stream) {
    const float* X    = (const float*)d_in[0];
    const int*   mask = (const int*)  d_in[1];
    const float* temb = (const float*)d_in[2];
    const float* Wq   = (const float*)d_in[3];
    const float* Wk   = (const float*)d_in[4];
    const float* Wv   = (const float*)d_in[5];
    const float* Wker = (const float*)d_in[6];
    const float* ffnW = (const float*)d_in[7];
    const float* ffnb = (const float*)d_in[8];
    const float* pa   = (const float*)d_in[9];
    float* out = (float*)d_out;

    __hip_bfloat16* Wb = (__hip_bfloat16*)d_ws;

    prep_kernel<<<256, 256, 0, stream>>>(Wk, Wv, Wb);
    pool_main<<<NB, 512, 0, stream>>>(X, mask, temb, Wq, Wker, ffnW, ffnb, pa, Wb, out);
}

// Round 19
// 289.321 us; speedup vs baseline: 2.2378x; 2.2378x over previous
//
#include <hip/hip_runtime.h>
#include <hip/hip_bf16.h>

// Problem constants
#define NB    2048   // batch
#define SS    200    // seq len
#define NTIL  13     // s-tiles of 16 (208 padded)
#define DSEQ  256
#define DITEM 64
#define AA    128    // attn dim (H=1, HD=128)

typedef __bf16 bf16x8 __attribute__((ext_vector_type(8)));
typedef float  f32x4  __attribute__((ext_vector_type(4)));

__device__ __forceinline__ float prelu_f(float x, float a) { return x >= 0.f ? x : a * x; }

// 16-lane reduce via DPP row_ror — VALU pipe only; result valid in all 16 lanes.
#define ROR_F(x, n) __int_as_float(__builtin_amdgcn_update_dpp(0, __float_as_int(x), 0x120 + (n), 0xf, 0xf, true))
__device__ __forceinline__ float row_sum16(float x) {
    x += ROR_F(x, 1); x += ROR_F(x, 2); x += ROR_F(x, 4); x += ROR_F(x, 8);
    return x;
}
__device__ __forceinline__ float row_max16(float x) {
    x = fmaxf(x, ROR_F(x, 1)); x = fmaxf(x, ROR_F(x, 2));
    x = fmaxf(x, ROR_F(x, 4)); x = fmaxf(x, ROR_F(x, 8));
    return x;
}

// ---------------- prep: W_k|W_v -> bf16 [256 rows][512B], XOR-swizzled within rows
// element (a,d) stored at byte (d*2) ^ ((a&7)<<4) of row a
__global__ void prep_kernel(const float* __restrict__ Wk, const float* __restrict__ Wv,
                            __hip_bfloat16* __restrict__ Wb) {
    int idx = blockIdx.x * 256 + threadIdx.x;   // 256 blocks -> 65536
    int a = idx >> 8, d = idx & 255;
    float v = (a < 128) ? Wk[a * 256 + d] : Wv[(a - 128) * 256 + d];
    int boff = (d * 2) ^ ((a & 7) << 4);
    Wb[a * 256 + (boff >> 1)] = __float2bfloat16(v);
}

// per-thread staging: thread handles row srow, 32B chunk `chunk` of the 16x256 f32 tile
#define ISSUE(tt)                                                               \
    {                                                                           \
        int r_ = (tt) * 16 + srow; r_ = r_ < SS ? r_ : SS - 1;                  \
        const float* xp_ = X + ((size_t)b * SS + r_) * DSEQ + chunk * 8;        \
        stlo = *reinterpret_cast<const f32x4*>(xp_);                            \
        sthi = *reinterpret_cast<const f32x4*>(xp_ + 4);                        \
    }

#define STAGE(buf)                                                              \
    {                                                                           \
        bf16x8 v_;                                                              \
        v_[0] = (__bf16)stlo[0]; v_[1] = (__bf16)stlo[1];                       \
        v_[2] = (__bf16)stlo[2]; v_[3] = (__bf16)stlo[3];                       \
        v_[4] = (__bf16)sthi[0]; v_[5] = (__bf16)sthi[1];                       \
        v_[6] = (__bf16)sthi[2]; v_[7] = (__bf16)sthi[3];                       \
        *reinterpret_cast<bf16x8*>(xbase + (buf) * 8192 + wr_off) = v_;         \
    }

// deferred online-softmax + V-fold of tile `tp` (scores of tp are in sp[tp&1])
#define SMFOLD(tp)                                                              \
    {                                                                           \
        const int q_ = (tp) & 1;                                                \
        const int s0_ = (tp) * 16;                                              \
        f32x4 r0_ = *reinterpret_cast<const f32x4*>(&sp[q_][c][0]);             \
        f32x4 r1_ = *reinterpret_cast<const f32x4*>(&sp[q_][c][4]);             \
        float sc_ = (r0_[0]+r0_[1]+r0_[2]+r0_[3]+r1_[0]+r1_[1]+r1_[2]+r1_[3]) * inv_scale; \
        sc_ = mask_lds[s0_ + c] ? -1e9f : sc_;                                  \
        if (tid < 16) score_buf[s0_ + tid] = sc_;                               \
        float tmax_ = row_max16(sc_);                                           \
        float nm_ = fmaxf(m, tmax_);                                            \
        float fs_ = __expf(m - nm_);                                            \
        float e_  = __expf(sc_ - nm_);                                          \
        float ls_ = row_sum16(e_);                                              \
        l = l * fs_ + ls_; m = nm_;                                             \
        oacc *= fs_;                                                            \
        _Pragma("unroll")                                                       \
        for (int i_ = 0; i_ < 4; i_++) {                                        \
            float ew_ = __shfl(e_, (lane & 48) | (rg * 4 + i_), 64);            \
            oacc += ew_ * prelu_f(aVp[i_], pa);                                 \
        }                                                                       \
    }

// ---------------- main: one BLOCK (8 waves) per batch row; cooperative LDS staging.
// ZERO weight registers (K and V streamed from L2). __launch_bounds__(512,4)
// empirically selects the 64-VGPR tier on this toolchain -> 8 waves/SIMD.
__global__ __launch_bounds__(512, 4)
void pool_main(
    const float* __restrict__ X,      // [2048,200,256]
    const int*   __restrict__ maskp,  // [2048,200] 1 = pad
    const float* __restrict__ temb,   // [2048,64]
    const float* __restrict__ Wq,     // [128,64]
    const float* __restrict__ Wker,   // [128,128]
    const float* __restrict__ ffnW,   // [256,128]
    const float* __restrict__ ffnb,   // [256]
    const float* __restrict__ prelu_a,
    const __hip_bfloat16* __restrict__ Wb,  // ws: swizzled bf16 weights [256][256]
    float* __restrict__ out)          // [2048*256] ffn, then [2048*200] attn
{
    __shared__ __hip_bfloat16 Xt[2][16][256];    // 16 KB, dbuf bf16 X tile (swizzled)
    __shared__ float sp[2][16][8];               // [par][s][wave] score partials
    __shared__ float score_buf[208];
    __shared__ float out_vec[AA];
    __shared__ float tq[DITEM];
    __shared__ float Qv[AA];
    __shared__ float uv[AA];
    __shared__ int   mask_lds[208];

    const int tid  = threadIdx.x;
    const int w    = tid >> 6;        // wave 0..7
    const int lane = tid & 63;
    const int c    = lane & 15;       // D col (a within wave's 16) / s in tile
    const int rg   = lane >> 4;       // k-group / D-row-group
    const int b    = blockIdx.x;
    const float pa = *prelu_a;
    const float inv_scale = 0.08838834764831845f;  // 1/sqrt(128)

    const int srow  = tid >> 5;       // staging row 0..15
    const int chunk = tid & 31;       // 32B chunk in row
    const int wr_off = srow * 512 + ((chunk * 16) ^ ((srow & 7) << 4));
    char* xbase = (char*)&Xt[0][0][0];
    const int rswz = (c & 7) << 4;

    // weight fragment base pointers (L2-resident, shared chip-wide)
    const char* kb = (const char*)Wb + (size_t)(16 * w + c) * 512;
    const char* vb = kb + 65536;

    // ---- small staging + X tile-0 issue
    if (tid < DITEM) tq[tid] = temb[(size_t)b * DITEM + tid];
    if (tid < 208)   mask_lds[tid] = (tid < SS) ? maskp[(size_t)b * SS + tid] : 1;
    f32x4 stlo, sthi;
    ISSUE(0);
    __syncthreads();

    // ---- Q = prelu(W_q @ t)
    if (tid < AA) {
        float acc = 0.f;
        #pragma unroll
        for (int d4 = 0; d4 < 16; d4++) {
            f32x4 tv = *reinterpret_cast<const f32x4*>(&tq[d4 * 4]);
            f32x4 wq4 = *reinterpret_cast<const f32x4*>(Wq + (size_t)tid * DITEM + d4 * 4);
            acc += wq4[0]*tv[0] + wq4[1]*tv[1] + wq4[2]*tv[2] + wq4[3]*tv[3];
        }
        Qv[tid] = prelu_f(acc, pa);
    }
    __syncthreads();

    // ---- u = W_kernel @ Q
    if (tid < AA) {
        float acc = 0.f;
        #pragma unroll
        for (int d4 = 0; d4 < 32; d4++) {
            f32x4 qv = *reinterpret_cast<const f32x4*>(&Qv[d4 * 4]);
            f32x4 wv4 = *reinterpret_cast<const f32x4*>(Wker + (size_t)tid * AA + d4 * 4);
            acc += wv4[0]*qv[0] + wv4[1]*qv[1] + wv4[2]*qv[2] + wv4[3]*qv[3];
        }
        uv[tid] = acc;
    }
    __syncthreads();
    const float uwK = uv[16 * w + c];

    // tile 0 -> LDS
    STAGE(0);
    __syncthreads();

    // ---- main loop: 1 barrier per tile, deferred softmax, zero weight regs
    float m = -INFINITY, l = 0.f, oacc = 0.f;
    f32x4 aVp = {0.f, 0.f, 0.f, 0.f};

    for (int t = 0; t < NTIL; t++) {
        if (t + 1 < NTIL) ISSUE(t + 1);

        const char* rb = xbase + (t & 1) * 8192 + c * 512;

        // deferred softmax + V-fold of tile t-1
        if (t > 0) SMFOLD(t - 1);

        // K/V MFMA: af from LDS, K/V frags from L2, all consumed immediately
        f32x4 aK = {0.f, 0.f, 0.f, 0.f};
        f32x4 aV = {0.f, 0.f, 0.f, 0.f};
        #pragma unroll
        for (int k = 0; k < 8; k++) {
            const int o = (k * 64 + rg * 16) ^ rswz;
            bf16x8 af = *reinterpret_cast<const bf16x8*>(rb + o);
            bf16x8 bk = *reinterpret_cast<const bf16x8*>(kb + o);   // L2 hit
            bf16x8 bv = *reinterpret_cast<const bf16x8*>(vb + o);   // L2 hit
            aK = __builtin_amdgcn_mfma_f32_16x16x32_bf16(af, bk, aK, 0, 0, 0);
            aV = __builtin_amdgcn_mfma_f32_16x16x32_bf16(af, bv, aV, 0, 0, 0);
        }
        float pr[4];
        #pragma unroll
        for (int i = 0; i < 4; i++) pr[i] = row_sum16(prelu_f(aK[i], pa) * uwK);
        if (c == 0) {
            #pragma unroll
            for (int i = 0; i < 4; i++) sp[t & 1][rg * 4 + i][w] = pr[i];
        }
        aVp = aV;

        // stage tile t+1 into the other buffer
        if (t + 1 < NTIL) STAGE((t + 1) & 1);
        __syncthreads();
    }

    // ---- epilogue: fold last tile, reduce, outputs
    SMFOLD(NTIL - 1);
    oacc += __shfl_xor(oacc, 16, 64);
    oacc += __shfl_xor(oacc, 32, 64);
    const float invl = 1.0f / l;
    if (lane < 16) out_vec[16 * w + lane] = oacc * invl;
    __syncthreads();

    // attn output [b][200]
    if (tid < SS)
        out[(size_t)NB * DSEQ + (size_t)b * SS + tid] = __expf(score_buf[tid] - m) * invl;

    // FFN: out[o] = prelu(b[o] + sum_a ov[a]*ffnW[o][a])
    if (tid < DSEQ) {
        float acc = ffnb[tid];
        #pragma unroll 8
        for (int a4 = 0; a4 < 32; a4++) {
            f32x4 ov = *reinterpret_cast<const f32x4*>(&out_vec[a4 * 4]);
            f32x4 wv4 = *reinterpret_cast<const f32x4*>(ffnW + (size_t)tid * AA + a4 * 4);
            acc += wv4[0]*ov[0] + wv4[1]*ov[1] + wv4[2]*ov[2] + wv4[3]*ov[3];
        }
        out[(size_t)b * DSEQ + tid] = prelu_f(acc, pa);
    }
}

extern "C" void kernel_launch(void* const* d_in, const int* in_sizes, int n_in,
                              void* d_out, int out_size, void* d_ws, size_t ws_size,
                              hipStream_t stream) {
    const float* X    = (const float*)d_in[0];
    const int*   mask = (const int*)  d_in[1];
    const float* temb = (const float*)d_in[2];
    const float* Wq   = (const float*)d_in[3];
    const float* Wk   = (const float*)d_in[4];
    const float* Wv   = (const float*)d_in[5];
    const float* Wker = (const float*)d_in[6];
    const float* ffnW = (const float*)d_in[7];
    const float* ffnb = (const float*)d_in[8];
    const float* pa   = (const float*)d_in[9];
    float* out = (float*)d_out;

    __hip_bfloat16* Wb = (__hip_bfloat16*)d_ws;

    prep_kernel<<<256, 256, 0, stream>>>(Wk, Wv, Wb);
    pool_main<<<NB, 512, 0, stream>>>(X, mask, temb, Wq, Wker, ffnW, ffnb, pa, Wb, out);
}

// Round 20
// 222.765 us; speedup vs baseline: 2.9064x; 1.2988x over previous
//
#include <hip/hip_runtime.h>
#include <hip/hip_bf16.h>

// Problem constants
#define NB    2048   // batch
#define SS    200    // seq len
#define NTIL  13     // s-tiles of 16 (208 padded)
#define DSEQ  256
#define DITEM 64
#define AA    128    // attn dim (H=1, HD=128)

typedef __bf16 bf16x8 __attribute__((ext_vector_type(8)));
typedef __bf16 bf16x4 __attribute__((ext_vector_type(4)));
typedef float  f32x4  __attribute__((ext_vector_type(4)));

__device__ __forceinline__ float prelu_f(float x, float a) { return x >= 0.f ? x : a * x; }

// 16-lane sum via DPP row_ror — VALU pipe only; result valid in all 16 lanes.
#define ROR_F(x, n) __int_as_float(__builtin_amdgcn_update_dpp(0, __float_as_int(x), 0x120 + (n), 0xf, 0xf, true))
__device__ __forceinline__ float row_sum16(float x) {
    x += ROR_F(x, 1); x += ROR_F(x, 2); x += ROR_F(x, 4); x += ROR_F(x, 8);
    return x;
}

// ---------------- prep: W_k|W_v -> bf16 [256 rows][512B], XOR-swizzled within rows
// element (a,d) stored at byte (d*2) ^ ((a&7)<<4) of row a
__global__ void prep_kernel(const float* __restrict__ Wk, const float* __restrict__ Wv,
                            __hip_bfloat16* __restrict__ Wb) {
    int idx = blockIdx.x * 256 + threadIdx.x;   // 256 blocks -> 65536
    int a = idx >> 8, d = idx & 255;
    float v = (a < 128) ? Wk[a * 256 + d] : Wv[(a - 128) * 256 + d];
    int boff = (d * 2) ^ ((a & 7) << 4);
    Wb[a * 256 + (boff >> 1)] = __float2bfloat16(v);
}

// per-thread staging: thread handles row srow, 32B chunk `chunk` of the 16x256 f32 tile
#define ISSUE(tt)                                                               \
    {                                                                           \
        int r_ = (tt) * 16 + srow; r_ = r_ < SS ? r_ : SS - 1;                  \
        const float* xp_ = X + ((size_t)b * SS + r_) * DSEQ + chunk * 8;        \
        stlo = *reinterpret_cast<const f32x4*>(xp_);                            \
        sthi = *reinterpret_cast<const f32x4*>(xp_ + 4);                        \
    }

#define STAGE(buf)                                                              \
    {                                                                           \
        bf16x8 v_;                                                              \
        v_[0] = (__bf16)stlo[0]; v_[1] = (__bf16)stlo[1];                       \
        v_[2] = (__bf16)stlo[2]; v_[3] = (__bf16)stlo[3];                       \
        v_[4] = (__bf16)sthi[0]; v_[5] = (__bf16)sthi[1];                       \
        v_[6] = (__bf16)sthi[2]; v_[7] = (__bf16)sthi[3];                       \
        *reinterpret_cast<bf16x8*>(xbase + (buf) * 8192 + wr_off) = v_;         \
    }

// ---------------- main: one BLOCK (8 waves) per batch row; NO online softmax.
// Per tile: MFMA K (scores) + MFMA V -> V results parked in LDS as bf16.
// One exact softmax + P*V matvec + FFN at the end. No cross-tile dependency.
__global__ __launch_bounds__(512, 2)
void pool_main(
    const float* __restrict__ X,      // [2048,200,256]
    const int*   __restrict__ maskp,  // [2048,200] 1 = pad
    const float* __restrict__ temb,   // [2048,64]
    const float* __restrict__ Wq,     // [128,64]
    const float* __restrict__ Wker,   // [128,128]
    const float* __restrict__ ffnW,   // [256,128]
    const float* __restrict__ ffnb,   // [256]
    const float* __restrict__ prelu_a,
    const __hip_bfloat16* __restrict__ Wb,  // ws: swizzled bf16 weights [256][256]
    float* __restrict__ out)          // [2048*256] ffn, then [2048*200] attn
{
    __shared__ __hip_bfloat16 Xt[2][16][256];     // 16 KB, dbuf bf16 X tile (swizzled)
    __shared__ __hip_bfloat16 Vlds[128][212];     // 54.3 KB, V[a][s] bf16 (pad 212)
    __shared__ float sp[NTIL][16][8];             // 6.7 KB score partials [t][s][wave]
    __shared__ float ebuf[208];
    __shared__ float ovec[AA];
    __shared__ float wred[2][8];

    const int tid  = threadIdx.x;
    const int w    = tid >> 6;        // wave 0..7
    const int lane = tid & 63;
    const int c    = lane & 15;       // D col (a within wave's 16) / s in tile
    const int rg   = lane >> 4;       // k-group / D-row-group
    const int b    = blockIdx.x;
    const float pa = *prelu_a;
    const float inv_scale = 0.08838834764831845f;  // 1/sqrt(128)

    const int srow  = tid >> 5;       // staging row 0..15
    const int chunk = tid & 31;       // 32B chunk in row
    const int wr_off = srow * 512 + ((chunk * 16) ^ ((srow & 7) << 4));
    char* xbase = (char*)&Xt[0][0][0];
    const int rswz = (c & 7) << 4;

    // prologue scratch overlaid on Vlds (dead before first V write)
    float* tq = (float*)&Vlds[0][0];     // 64 f
    float* Qv = tq + 64;                 // 128 f
    float* uv = Qv + 128;                // 128 f

    // weight bases: K streamed from L2; V fragments hoisted to VGPRs
    const char* kb = (const char*)Wb + (size_t)(16 * w + c) * 512;
    const char* vbp = kb + 65536;
    bf16x8 wv[8];
    #pragma unroll
    for (int k = 0; k < 8; k++)
        wv[k] = *reinterpret_cast<const bf16x8*>(vbp + ((k * 64 + rg * 16) ^ rswz));

    // ---- small staging + X tile-0 issue
    if (tid < DITEM) tq[tid] = temb[(size_t)b * DITEM + tid];
    f32x4 stlo, sthi;
    ISSUE(0);
    __syncthreads();

    // ---- Q = prelu(W_q @ t)
    if (tid < AA) {
        float acc = 0.f;
        #pragma unroll
        for (int d4 = 0; d4 < 16; d4++) {
            f32x4 tv = *reinterpret_cast<const f32x4*>(&tq[d4 * 4]);
            f32x4 wq4 = *reinterpret_cast<const f32x4*>(Wq + (size_t)tid * DITEM + d4 * 4);
            acc += wq4[0]*tv[0] + wq4[1]*tv[1] + wq4[2]*tv[2] + wq4[3]*tv[3];
        }
        Qv[tid] = prelu_f(acc, pa);
    }
    __syncthreads();

    // ---- u = W_kernel @ Q
    if (tid < AA) {
        float acc = 0.f;
        #pragma unroll
        for (int d4 = 0; d4 < 32; d4++) {
            f32x4 qv = *reinterpret_cast<const f32x4*>(&Qv[d4 * 4]);
            f32x4 wv4 = *reinterpret_cast<const f32x4*>(Wker + (size_t)tid * AA + d4 * 4);
            acc += wv4[0]*qv[0] + wv4[1]*qv[1] + wv4[2]*qv[2] + wv4[3]*qv[3];
        }
        uv[tid] = acc;
    }
    __syncthreads();
    const float uwK = uv[16 * w + c];     // register; uv region dead after the next barrier

    // tile 0 -> LDS
    STAGE(0);
    __syncthreads();

    // ---- main loop: 1 barrier/tile, NO serial softmax state
    for (int t = 0; t < NTIL; t++) {
        if (t + 1 < NTIL) ISSUE(t + 1);

        const char* rb = xbase + (t & 1) * 8192 + c * 512;

        f32x4 aK = {0.f, 0.f, 0.f, 0.f};
        f32x4 aV = {0.f, 0.f, 0.f, 0.f};
        #pragma unroll
        for (int k = 0; k < 8; k++) {
            const int o = (k * 64 + rg * 16) ^ rswz;
            bf16x8 af = *reinterpret_cast<const bf16x8*>(rb + o);
            bf16x8 bk = *reinterpret_cast<const bf16x8*>(kb + o);   // L2 hit
            aK = __builtin_amdgcn_mfma_f32_16x16x32_bf16(af, bk, aK, 0, 0, 0);
            aV = __builtin_amdgcn_mfma_f32_16x16x32_bf16(af, wv[k], aV, 0, 0, 0);
        }

        // score partials for this wave's 16 K-cols
        float pr[4];
        #pragma unroll
        for (int i = 0; i < 4; i++) pr[i] = row_sum16(prelu_f(aK[i], pa) * uwK);
        if (c == 0) {
            #pragma unroll
            for (int i = 0; i < 4; i++) sp[t][rg * 4 + i][w] = pr[i];
        }

        // park prelu'd V in LDS: row = a (16w+c), cols = t*16+rg*4..+3
        bf16x4 vv;
        #pragma unroll
        for (int i = 0; i < 4; i++) vv[i] = (__bf16)prelu_f(aV[i], pa);
        *reinterpret_cast<bf16x4*>(&Vlds[16 * w + c][t * 16 + rg * 4]) = vv;

        if (t + 1 < NTIL) STAGE((t + 1) & 1);
        __syncthreads();
    }

    // ---- finalize: exact softmax over 208 scores
    float sc = -1e9f;
    if (tid < 208) {
        f32x4 r0 = *reinterpret_cast<const f32x4*>(&sp[tid >> 4][tid & 15][0]);
        f32x4 r1 = *reinterpret_cast<const f32x4*>(&sp[tid >> 4][tid & 15][4]);
        float s8 = r0[0]+r0[1]+r0[2]+r0[3]+r1[0]+r1[1]+r1[2]+r1[3];
        int mk = (tid < SS) ? maskp[(size_t)b * SS + tid] : 1;
        sc = mk ? -1e9f : s8 * inv_scale;
    }
    float v = sc;
    #pragma unroll
    for (int o = 1; o < 64; o <<= 1) v = fmaxf(v, __shfl_xor(v, o, 64));
    if (lane == 0) wred[0][w] = v;
    __syncthreads();
    float mx = wred[0][0];
    #pragma unroll
    for (int i = 1; i < 8; i++) mx = fmaxf(mx, wred[0][i]);
    float e = (tid < 208) ? __expf(sc - mx) : 0.f;
    if (tid < 208) ebuf[tid] = e;
    float sv = e;
    #pragma unroll
    for (int o = 1; o < 64; o <<= 1) sv += __shfl_xor(sv, o, 64);
    if (lane == 0) wred[1][w] = sv;
    __syncthreads();
    float l = wred[1][0];
    #pragma unroll
    for (int i = 1; i < 8; i++) l += wred[1][i];
    const float invl = 1.0f / l;

    // attn output [b][200]
    if (tid < SS)
        out[(size_t)NB * DSEQ + (size_t)b * SS + tid] = ebuf[tid] * invl;

    // P*V matvec: thread a (<128) sums over all 208 s
    if (tid < AA) {
        float acc = 0.f;
        #pragma unroll 4
        for (int sq = 0; sq < 52; sq++) {
            bf16x4 vv = *reinterpret_cast<const bf16x4*>(&Vlds[tid][sq * 4]);
            f32x4  ee = *reinterpret_cast<const f32x4*>(&ebuf[sq * 4]);
            acc += ee[0]*(float)vv[0] + ee[1]*(float)vv[1]
                 + ee[2]*(float)vv[2] + ee[3]*(float)vv[3];
        }
        ovec[tid] = acc * invl;
    }
    __syncthreads();

    // FFN: out[o] = prelu(b[o] + sum_a ov[a]*ffnW[o][a])
    if (tid < DSEQ) {
        float acc = ffnb[tid];
        #pragma unroll 8
        for (int a4 = 0; a4 < 32; a4++) {
            f32x4 ov = *reinterpret_cast<const f32x4*>(&ovec[a4 * 4]);
            f32x4 wv4 = *reinterpret_cast<const f32x4*>(ffnW + (size_t)tid * AA + a4 * 4);
            acc += wv4[0]*ov[0] + wv4[1]*ov[1] + wv4[2]*ov[2] + wv4[3]*ov[3];
        }
        out[(size_t)b * DSEQ + tid] = prelu_f(acc, pa);
    }
}

extern "C" void kernel_launch(void* const* d_in, const int* in_sizes, int n_in,
                              void* d_out, int out_size, void* d_ws, size_t ws_size,
                              hipStream_t stream) {
    const float* X    = (const float*)d_in[0];
    const int*   mask = (const int*)  d_in[1];
    const float* temb = (const float*)d_in[2];
    const float* Wq   = (const float*)d_in[3];
    const float* Wk   = (const float*)d_in[4];
    const float* Wv   = (const float*)d_in[5];
    const float* Wker = (const float*)d_in[6];
    const float* ffnW = (const float*)d_in[7];
    const float* ffnb = (const float*)d_in[8];
    const float* pa   = (const float*)d_in[9];
    float* out = (float*)d_out;

    __hip_bfloat16* Wb = (__hip_bfloat16*)d_ws;

    prep_kernel<<<256, 256, 0, stream>>>(Wk, Wv, Wb);
    pool_main<<<NB, 512, 0, stream>>>(X, mask, temb, Wq, Wker, ffnW, ffnb, pa, Wb, out);
}

// Round 21
// 154.013 us; speedup vs baseline: 4.2038x; 1.4464x over previous
//
#include <hip/hip_runtime.h>
#include <hip/hip_bf16.h>

// Problem constants
#define NB    2048   // batch
#define SS    200    // seq len
#define NTIL  13     // s-tiles of 16 (208 padded)
#define DSEQ  256
#define DITEM 64
#define AA    128    // attn dim (H=1, HD=128)
#define NS    4      // batch rows (streams) per block

typedef __bf16 bf16x8 __attribute__((ext_vector_type(8)));
typedef float  f32x4  __attribute__((ext_vector_type(4)));

__device__ __forceinline__ float prelu_f(float x, float a) { return x >= 0.f ? x : a * x; }

// 16-lane reduce via DPP row_ror — VALU pipe only; result valid in all 16 lanes.
#define ROR_F(x, n) __int_as_float(__builtin_amdgcn_update_dpp(0, __float_as_int(x), 0x120 + (n), 0xf, 0xf, true))
__device__ __forceinline__ float row_sum16(float x) {
    x += ROR_F(x, 1); x += ROR_F(x, 2); x += ROR_F(x, 4); x += ROR_F(x, 8);
    return x;
}
__device__ __forceinline__ float row_max16(float x) {
    x = fmaxf(x, ROR_F(x, 1)); x = fmaxf(x, ROR_F(x, 2));
    x = fmaxf(x, ROR_F(x, 4)); x = fmaxf(x, ROR_F(x, 8));
    return x;
}

// ---------------- prep: W_k|W_v -> bf16 [256 rows][512B], XOR-swizzled within rows
// element (a,d) stored at byte (d*2) ^ ((a&7)<<4) of row a
__global__ void prep_kernel(const float* __restrict__ Wk, const float* __restrict__ Wv,
                            __hip_bfloat16* __restrict__ Wb) {
    int idx = blockIdx.x * 256 + threadIdx.x;   // 256 blocks -> 65536
    int a = idx >> 8, d = idx & 255;
    float v = (a < 128) ? Wk[a * 256 + d] : Wv[(a - 128) * 256 + d];
    int boff = (d * 2) ^ ((a & 7) << 4);
    Wb[a * 256 + (boff >> 1)] = __float2bfloat16(v);
}

// staging (single shared st-register set; streams staged sequentially)
#define ISSUE(tt, s)                                                            \
    {                                                                           \
        int r_ = (tt) * 16 + srow; r_ = r_ < SS ? r_ : SS - 1;                  \
        const float* xp_ = X + ((size_t)(b0 + (s)) * SS + r_) * DSEQ + chunk * 8; \
        stlo = *reinterpret_cast<const f32x4*>(xp_);                            \
        sthi = *reinterpret_cast<const f32x4*>(xp_ + 4);                        \
    }

#define STAGE(tt, s)                                                            \
    {                                                                           \
        bf16x8 v_;                                                              \
        v_[0] = (__bf16)stlo[0]; v_[1] = (__bf16)stlo[1];                       \
        v_[2] = (__bf16)stlo[2]; v_[3] = (__bf16)stlo[3];                       \
        v_[4] = (__bf16)sthi[0]; v_[5] = (__bf16)sthi[1];                       \
        v_[6] = (__bf16)sthi[2]; v_[7] = (__bf16)sthi[3];                       \
        *reinterpret_cast<bf16x8*>(xbase + (s) * 16384 + ((tt) & 1) * 8192 + wr_off) = v_; \
    }

// deferred online-softmax + V-fold of tile `tp`, stream s (literal token)
#define SMFOLD(tp, s)                                                           \
    {                                                                           \
        const int q_ = (tp) & 1;                                                \
        const int s0_ = (tp) * 16;                                              \
        f32x4 r0_ = *reinterpret_cast<const f32x4*>(&sp[s][q_][c][0]);          \
        f32x4 r1_ = *reinterpret_cast<const f32x4*>(&sp[s][q_][c][4]);          \
        float sc_ = (r0_[0]+r0_[1]+r0_[2]+r0_[3]+r1_[0]+r1_[1]+r1_[2]+r1_[3]) * inv_scale; \
        sc_ = mask_lds[s][s0_ + c] ? -1e9f : sc_;                               \
        if (tid < 16) arena[s][s0_ + tid] = sc_;                                \
        float tmax_ = row_max16(sc_);                                           \
        float nm_ = fmaxf(m##s, tmax_);                                         \
        float fs_ = __expf(m##s - nm_);                                         \
        float e_  = __expf(sc_ - nm_);                                          \
        float ls_ = row_sum16(e_);                                              \
        l##s = l##s * fs_ + ls_; m##s = nm_;                                    \
        oacc##s *= fs_;                                                         \
        _Pragma("unroll")                                                       \
        for (int i_ = 0; i_ < 4; i_++) {                                        \
            float ew_ = __shfl(e_, (lane & 48) | (rg * 4 + i_), 64);            \
            oacc##s += ew_ * prelu_f(aVp##s[i_], pa);                           \
        }                                                                       \
    }

// compute tile tt, stream s: af from LDS, K/V frags from L2 (shared chip-wide)
#define COMPUTE(tt, s)                                                          \
    {                                                                           \
        const char* rb_ = xbase + (s) * 16384 + ((tt) & 1) * 8192 + c * 512;    \
        f32x4 aK = {0.f,0.f,0.f,0.f}, aV = {0.f,0.f,0.f,0.f};                   \
        _Pragma("unroll")                                                       \
        for (int k = 0; k < 8; k++) {                                           \
            const int o = (k * 64 + rg * 16) ^ rswz;                            \
            bf16x8 af = *reinterpret_cast<const bf16x8*>(rb_ + o);              \
            bf16x8 bk = *reinterpret_cast<const bf16x8*>(kb + o);               \
            bf16x8 bv = *reinterpret_cast<const bf16x8*>(vb + o);               \
            aK = __builtin_amdgcn_mfma_f32_16x16x32_bf16(af, bk, aK, 0, 0, 0);  \
            aV = __builtin_amdgcn_mfma_f32_16x16x32_bf16(af, bv, aV, 0, 0, 0);  \
        }                                                                       \
        float pr_[4];                                                           \
        _Pragma("unroll")                                                       \
        for (int i = 0; i < 4; i++) pr_[i] = row_sum16(prelu_f(aK[i], pa) * uw##s); \
        if (c == 0) {                                                           \
            _Pragma("unroll")                                                   \
            for (int i = 0; i < 4; i++) sp[s][(tt) & 1][rg * 4 + i][w] = pr_[i]; \
        }                                                                       \
        aVp##s = aV;                                                            \
    }

// ---------------- main: one BLOCK (8 waves) per FOUR batch rows.
// grid = 512 blocks = exactly 2/CU -> single resident generation.
// K and V streamed from L2, shared by all 4 streams; st regs shared.
__global__ __launch_bounds__(512, 2)
void pool_main(
    const float* __restrict__ X,      // [2048,200,256]
    const int*   __restrict__ maskp,  // [2048,200] 1 = pad
    const float* __restrict__ temb,   // [2048,64]
    const float* __restrict__ Wq,     // [128,64]
    const float* __restrict__ Wker,   // [128,128]
    const float* __restrict__ ffnW,   // [256,128]
    const float* __restrict__ ffnb,   // [256]
    const float* __restrict__ prelu_a,
    const __hip_bfloat16* __restrict__ Wb,  // ws: swizzled bf16 weights [256][256]
    float* __restrict__ out)          // [2048*256] ffn, then [2048*200] attn
{
    __shared__ __hip_bfloat16 Xt[NS][2][16][256];   // 64 KB, dbuf bf16 X tiles
    __shared__ float sp[NS][2][16][8];              // 4 KB score partials
    __shared__ float arena[NS][336];                // 5.25 KB: prologue tq/Qv/uv, then score[208]+ovec[128]
    __shared__ int   mask_lds[NS][208];             // 3.25 KB

    const int tid  = threadIdx.x;
    const int w    = tid >> 6;        // wave 0..7
    const int lane = tid & 63;
    const int c    = lane & 15;
    const int rg   = lane >> 4;
    const int b0   = blockIdx.x * NS;
    const float pa = *prelu_a;
    const float inv_scale = 0.08838834764831845f;  // 1/sqrt(128)

    const int srow  = tid >> 5;       // staging row 0..15
    const int chunk = tid & 31;       // 32B chunk in row
    const int wr_off = srow * 512 + ((chunk * 16) ^ ((srow & 7) << 4));
    char* xbase = (char*)&Xt[0][0][0][0];
    const int rswz = (c & 7) << 4;

    // weight fragment bases (L2-resident, shared chip-wide and across streams)
    const char* kb = (const char*)Wb + (size_t)(16 * w + c) * 512;
    const char* vb = kb + 65536;

    // ---- prologue: masks, temb; Q and u per stream (128 threads each)
    const int ps = tid >> 7;          // prologue stream 0..3
    const int po = tid & 127;
    #pragma unroll
    for (int s = 0; s < NS; s++)
        if (tid < 208) mask_lds[s][tid] = (tid < SS) ? maskp[(size_t)(b0 + s) * SS + tid] : 1;
    if (po < DITEM) arena[ps][po] = temb[(size_t)(b0 + ps) * DITEM + po];
    __syncthreads();

    // Q = prelu(W_q @ t)  -> arena[ps][64+po]
    {
        float acc = 0.f;
        #pragma unroll
        for (int d4 = 0; d4 < 16; d4++) {
            f32x4 tv = *reinterpret_cast<const f32x4*>(&arena[ps][d4 * 4]);
            f32x4 wq4 = *reinterpret_cast<const f32x4*>(Wq + (size_t)po * DITEM + d4 * 4);
            acc += wq4[0]*tv[0] + wq4[1]*tv[1] + wq4[2]*tv[2] + wq4[3]*tv[3];
        }
        __syncthreads();
        arena[ps][64 + po] = prelu_f(acc, pa);
    }
    __syncthreads();

    // u = W_kernel @ Q -> arena[ps][192+po]
    {
        float acc = 0.f;
        #pragma unroll
        for (int d4 = 0; d4 < 32; d4++) {
            f32x4 qv = *reinterpret_cast<const f32x4*>(&arena[ps][64 + d4 * 4]);
            f32x4 wk4 = *reinterpret_cast<const f32x4*>(Wker + (size_t)po * AA + d4 * 4);
            acc += wk4[0]*qv[0] + wk4[1]*qv[1] + wk4[2]*qv[2] + wk4[3]*qv[3];
        }
        arena[ps][192 + po] = acc;
    }
    __syncthreads();
    const float uw0 = arena[0][192 + 16 * w + c];
    const float uw1 = arena[1][192 + 16 * w + c];
    const float uw2 = arena[2][192 + 16 * w + c];
    const float uw3 = arena[3][192 + 16 * w + c];

    // ---- stage tile 0 for all 4 streams (shared st regs, sequential)
    f32x4 stlo, sthi;
    ISSUE(0, 0); STAGE(0, 0);
    ISSUE(0, 1); STAGE(0, 1);
    ISSUE(0, 2); STAGE(0, 2);
    ISSUE(0, 3); STAGE(0, 3);
    __syncthreads();

    // ---- main loop: 1 barrier/tile, 4 independent streams interleaved
    float m0 = -INFINITY, l0 = 0.f, oacc0 = 0.f;
    float m1 = -INFINITY, l1 = 0.f, oacc1 = 0.f;
    float m2 = -INFINITY, l2 = 0.f, oacc2 = 0.f;
    float m3 = -INFINITY, l3 = 0.f, oacc3 = 0.f;
    f32x4 aVp0 = {0.f,0.f,0.f,0.f}, aVp1 = {0.f,0.f,0.f,0.f};
    f32x4 aVp2 = {0.f,0.f,0.f,0.f}, aVp3 = {0.f,0.f,0.f,0.f};

    for (int t = 0; t < NTIL; t++) {
        const int more = (t + 1 < NTIL);

        if (more) ISSUE(t + 1, 0);
        if (t > 0) SMFOLD(t - 1, 0);
        COMPUTE(t, 0);
        if (more) STAGE(t + 1, 0);

        if (more) ISSUE(t + 1, 1);
        if (t > 0) SMFOLD(t - 1, 1);
        COMPUTE(t, 1);
        if (more) STAGE(t + 1, 1);

        if (more) ISSUE(t + 1, 2);
        if (t > 0) SMFOLD(t - 1, 2);
        COMPUTE(t, 2);
        if (more) STAGE(t + 1, 2);

        if (more) ISSUE(t + 1, 3);
        if (t > 0) SMFOLD(t - 1, 3);
        COMPUTE(t, 3);
        if (more) STAGE(t + 1, 3);

        __syncthreads();
    }

    // ---- epilogue: fold last tile (sp published by final barrier)
    SMFOLD(NTIL - 1, 0); SMFOLD(NTIL - 1, 1);
    SMFOLD(NTIL - 1, 2); SMFOLD(NTIL - 1, 3);

    oacc0 += __shfl_xor(oacc0, 16, 64); oacc0 += __shfl_xor(oacc0, 32, 64);
    oacc1 += __shfl_xor(oacc1, 16, 64); oacc1 += __shfl_xor(oacc1, 32, 64);
    oacc2 += __shfl_xor(oacc2, 16, 64); oacc2 += __shfl_xor(oacc2, 32, 64);
    oacc3 += __shfl_xor(oacc3, 16, 64); oacc3 += __shfl_xor(oacc3, 32, 64);
    const float invl0 = 1.0f / l0, invl1 = 1.0f / l1;
    const float invl2 = 1.0f / l2, invl3 = 1.0f / l3;
    if (lane < 16) {
        arena[0][208 + 16 * w + lane] = oacc0 * invl0;
        arena[1][208 + 16 * w + lane] = oacc1 * invl1;
        arena[2][208 + 16 * w + lane] = oacc2 * invl2;
        arena[3][208 + 16 * w + lane] = oacc3 * invl3;
    }
    __syncthreads();

    // attn outputs (m/l/invl are block-uniform)
    if (tid < SS) {
        out[(size_t)NB * DSEQ + (size_t)(b0 + 0) * SS + tid] = __expf(arena[0][tid] - m0) * invl0;
        out[(size_t)NB * DSEQ + (size_t)(b0 + 1) * SS + tid] = __expf(arena[1][tid] - m1) * invl1;
        out[(size_t)NB * DSEQ + (size_t)(b0 + 2) * SS + tid] = __expf(arena[2][tid] - m2) * invl2;
        out[(size_t)NB * DSEQ + (size_t)(b0 + 3) * SS + tid] = __expf(arena[3][tid] - m3) * invl3;
    }

    // FFN: thread handles output o for streams sA and sA+2 (ffnW row read once)
    {
        const int o  = tid & 255;
        const int sA = tid >> 8;       // 0 or 1
        float accA = ffnb[o], accB = accA;
        #pragma unroll 8
        for (int a4 = 0; a4 < 32; a4++) {
            f32x4 wv4 = *reinterpret_cast<const f32x4*>(ffnW + (size_t)o * AA + a4 * 4);
            f32x4 ovA = *reinterpret_cast<const f32x4*>(&arena[sA][208 + a4 * 4]);
            f32x4 ovB = *reinterpret_cast<const f32x4*>(&arena[sA + 2][208 + a4 * 4]);
            accA += wv4[0]*ovA[0] + wv4[1]*ovA[1] + wv4[2]*ovA[2] + wv4[3]*ovA[3];
            accB += wv4[0]*ovB[0] + wv4[1]*ovB[1] + wv4[2]*ovB[2] + wv4[3]*ovB[3];
        }
        out[(size_t)(b0 + sA) * DSEQ + o]     = prelu_f(accA, pa);
        out[(size_t)(b0 + sA + 2) * DSEQ + o] = prelu_f(accB, pa);
    }
}

extern "C" void kernel_launch(void* const* d_in, const int* in_sizes, int n_in,
                              void* d_out, int out_size, void* d_ws, size_t ws_size,
                              hipStream_t stream) {
    const float* X    = (const float*)d_in[0];
    const int*   mask = (const int*)  d_in[1];
    const float* temb = (const float*)d_in[2];
    const float* Wq   = (const float*)d_in[3];
    const float* Wk   = (const float*)d_in[4];
    const float* Wv   = (const float*)d_in[5];
    const float* Wker = (const float*)d_in[6];
    const float* ffnW = (const float*)d_in[7];
    const float* ffnb = (const float*)d_in[8];
    const float* pa   = (const float*)d_in[9];
    float* out = (float*)d_out;

    __hip_bfloat16* Wb = (__hip_bfloat16*)d_ws;

    prep_kernel<<<256, 256, 0, stream>>>(Wk, Wv, Wb);
    pool_main<<<NB / NS, 512, 0, stream>>>(X, mask, temb, Wq, Wker, ffnW, ffnb, pa, Wb, out);
}

// Round 22
// 149.221 us; speedup vs baseline: 4.3388x; 1.0321x over previous
//
#include <hip/hip_runtime.h>
#include <hip/hip_bf16.h>

// Problem constants
#define NB    2048   // batch
#define SS    200    // seq len
#define NTIL  13     // s-tiles of 16 (208 padded)
#define DSEQ  256
#define DITEM 64
#define AA    128    // attn dim (H=1, HD=128)
#define NS    4      // batch rows (streams) per block

typedef __bf16 bf16x8 __attribute__((ext_vector_type(8)));
typedef float  f32x4  __attribute__((ext_vector_type(4)));

__device__ __forceinline__ float prelu_f(float x, float a) { return x >= 0.f ? x : a * x; }

// 16-lane reduce via DPP row_ror — VALU pipe only; result valid in all 16 lanes.
#define ROR_F(x, n) __int_as_float(__builtin_amdgcn_update_dpp(0, __float_as_int(x), 0x120 + (n), 0xf, 0xf, true))
__device__ __forceinline__ float row_sum16(float x) {
    x += ROR_F(x, 1); x += ROR_F(x, 2); x += ROR_F(x, 4); x += ROR_F(x, 8);
    return x;
}
__device__ __forceinline__ float row_max16(float x) {
    x = fmaxf(x, ROR_F(x, 1)); x = fmaxf(x, ROR_F(x, 2));
    x = fmaxf(x, ROR_F(x, 4)); x = fmaxf(x, ROR_F(x, 8));
    return x;
}

// ---------------- prep: W_k|W_v -> bf16 [256 rows][512B], XOR-swizzled within rows
__global__ void prep_kernel(const float* __restrict__ Wk, const float* __restrict__ Wv,
                            __hip_bfloat16* __restrict__ Wb) {
    int idx = blockIdx.x * 256 + threadIdx.x;   // 256 blocks -> 65536
    int a = idx >> 8, d = idx & 255;
    float v = (a < 128) ? Wk[a * 256 + d] : Wv[(a - 128) * 256 + d];
    int boff = (d * 2) ^ ((a & 7) << 4);
    Wb[a * 256 + (boff >> 1)] = __float2bfloat16(v);
}

// staging with two register sets (A/B) so load->stage distance >= half epoch
#define ISSUE_R(tt, s, L, H)                                                    \
    {                                                                           \
        int r_ = (tt) * 16 + srow; r_ = r_ < SS ? r_ : SS - 1;                  \
        const float* xp_ = X + ((size_t)(b0 + (s)) * SS + r_) * DSEQ + chunk * 8; \
        L = *reinterpret_cast<const f32x4*>(xp_);                               \
        H = *reinterpret_cast<const f32x4*>(xp_ + 4);                           \
    }

#define STAGE_R(tt, s, L, H)                                                    \
    {                                                                           \
        bf16x8 v_;                                                              \
        v_[0] = (__bf16)L[0]; v_[1] = (__bf16)L[1];                             \
        v_[2] = (__bf16)L[2]; v_[3] = (__bf16)L[3];                             \
        v_[4] = (__bf16)H[0]; v_[5] = (__bf16)H[1];                             \
        v_[6] = (__bf16)H[2]; v_[7] = (__bf16)H[3];                             \
        *reinterpret_cast<bf16x8*>(xbase + (s) * 16384 + ((tt) & 1) * 8192 + wr_off) = v_; \
    }

// deferred online-softmax + V-fold of tile `tp`, stream s (literal token)
#define SMFOLD(tp, s)                                                           \
    {                                                                           \
        const int q_ = (tp) & 1;                                                \
        const int s0_ = (tp) * 16;                                              \
        f32x4 r0_ = *reinterpret_cast<const f32x4*>(&sp[s][q_][c][0]);          \
        f32x4 r1_ = *reinterpret_cast<const f32x4*>(&sp[s][q_][c][4]);          \
        float sc_ = (r0_[0]+r0_[1]+r0_[2]+r0_[3]+r1_[0]+r1_[1]+r1_[2]+r1_[3]) * inv_scale; \
        sc_ = mask_lds[s][s0_ + c] ? -1e9f : sc_;                               \
        if (tid < 16) arena[s][s0_ + tid] = sc_;                                \
        float tmax_ = row_max16(sc_);                                           \
        float nm_ = fmaxf(m##s, tmax_);                                         \
        float fs_ = __expf(m##s - nm_);                                         \
        float e_  = __expf(sc_ - nm_);                                          \
        float ls_ = row_sum16(e_);                                              \
        l##s = l##s * fs_ + ls_; m##s = nm_;                                    \
        oacc##s *= fs_;                                                         \
        _Pragma("unroll")                                                       \
        for (int i_ = 0; i_ < 4; i_++) {                                        \
            float ew_ = __shfl(e_, (lane & 48) | (rg * 4 + i_), 64);            \
            oacc##s += ew_ * prelu_f(aVp##s[i_], pa);                           \
        }                                                                       \
    }

// fused half-compute over k = k0..k0+3: weights loaded ONCE, used by all 4 streams
#define CHALF(k0)                                                               \
    _Pragma("unroll")                                                           \
    for (int k = (k0); k < (k0) + 4; k++) {                                     \
        const int o = (k * 64 + rg * 16) ^ rswz;                                \
        bf16x8 bk  = *reinterpret_cast<const bf16x8*>(kb + o);                  \
        bf16x8 bv  = *reinterpret_cast<const bf16x8*>(vb + o);                  \
        bf16x8 af0 = *reinterpret_cast<const bf16x8*>(rb0 + o);                 \
        bf16x8 af1 = *reinterpret_cast<const bf16x8*>(rb1 + o);                 \
        bf16x8 af2 = *reinterpret_cast<const bf16x8*>(rb2 + o);                 \
        bf16x8 af3 = *reinterpret_cast<const bf16x8*>(rb3 + o);                 \
        aK0 = __builtin_amdgcn_mfma_f32_16x16x32_bf16(af0, bk, aK0, 0, 0, 0);   \
        aVp0 = __builtin_amdgcn_mfma_f32_16x16x32_bf16(af0, bv, aVp0, 0, 0, 0); \
        aK1 = __builtin_amdgcn_mfma_f32_16x16x32_bf16(af1, bk, aK1, 0, 0, 0);   \
        aVp1 = __builtin_amdgcn_mfma_f32_16x16x32_bf16(af1, bv, aVp1, 0, 0, 0); \
        aK2 = __builtin_amdgcn_mfma_f32_16x16x32_bf16(af2, bk, aK2, 0, 0, 0);   \
        aVp2 = __builtin_amdgcn_mfma_f32_16x16x32_bf16(af2, bv, aVp2, 0, 0, 0); \
        aK3 = __builtin_amdgcn_mfma_f32_16x16x32_bf16(af3, bk, aK3, 0, 0, 0);   \
        aVp3 = __builtin_amdgcn_mfma_f32_16x16x32_bf16(af3, bv, aVp3, 0, 0, 0); \
    }

#define SCOREPART(tt, s)                                                        \
    {                                                                           \
        float pr_[4];                                                           \
        _Pragma("unroll")                                                       \
        for (int i = 0; i < 4; i++) pr_[i] = row_sum16(prelu_f(aK##s[i], pa) * uw##s); \
        if (c == 0) {                                                           \
            _Pragma("unroll")                                                   \
            for (int i = 0; i < 4; i++) sp[s][(tt) & 1][rg * 4 + i][w] = pr_[i]; \
        }                                                                       \
    }

// ---------------- main: one BLOCK (8 waves) per FOUR batch rows; fused k-loop
// loads each K/V weight fragment ONCE per epoch (shared across 4 streams).
__global__ __launch_bounds__(512, 2)
void pool_main(
    const float* __restrict__ X,      // [2048,200,256]
    const int*   __restrict__ maskp,  // [2048,200] 1 = pad
    const float* __restrict__ temb,   // [2048,64]
    const float* __restrict__ Wq,     // [128,64]
    const float* __restrict__ Wker,   // [128,128]
    const float* __restrict__ ffnW,   // [256,128]
    const float* __restrict__ ffnb,   // [256]
    const float* __restrict__ prelu_a,
    const __hip_bfloat16* __restrict__ Wb,  // ws: swizzled bf16 weights [256][256]
    float* __restrict__ out)          // [2048*256] ffn, then [2048*200] attn
{
    __shared__ __hip_bfloat16 Xt[NS][2][16][256];   // 64 KB, dbuf bf16 X tiles
    __shared__ float sp[NS][2][16][8];              // 4 KB score partials
    __shared__ float arena[NS][336];                // 5.25 KB
    __shared__ int   mask_lds[NS][208];             // 3.25 KB

    const int tid  = threadIdx.x;
    const int w    = tid >> 6;        // wave 0..7
    const int lane = tid & 63;
    const int c    = lane & 15;
    const int rg   = lane >> 4;
    const int b0   = blockIdx.x * NS;
    const float pa = *prelu_a;
    const float inv_scale = 0.08838834764831845f;  // 1/sqrt(128)

    const int srow  = tid >> 5;       // staging row 0..15
    const int chunk = tid & 31;       // 32B chunk in row
    const int wr_off = srow * 512 + ((chunk * 16) ^ ((srow & 7) << 4));
    char* xbase = (char*)&Xt[0][0][0][0];
    const int rswz = (c & 7) << 4;

    // weight fragment bases (L2-resident, shared chip-wide and across streams)
    const char* kb = (const char*)Wb + (size_t)(16 * w + c) * 512;
    const char* vb = kb + 65536;

    // ---- prologue: masks, temb; Q and u per stream (128 threads each)
    const int ps = tid >> 7;          // prologue stream 0..3
    const int po = tid & 127;
    #pragma unroll
    for (int s = 0; s < NS; s++)
        if (tid < 208) mask_lds[s][tid] = (tid < SS) ? maskp[(size_t)(b0 + s) * SS + tid] : 1;
    if (po < DITEM) arena[ps][po] = temb[(size_t)(b0 + ps) * DITEM + po];
    __syncthreads();

    // Q = prelu(W_q @ t) -> arena[ps][64+po]
    {
        float acc = 0.f;
        #pragma unroll
        for (int d4 = 0; d4 < 16; d4++) {
            f32x4 tv = *reinterpret_cast<const f32x4*>(&arena[ps][d4 * 4]);
            f32x4 wq4 = *reinterpret_cast<const f32x4*>(Wq + (size_t)po * DITEM + d4 * 4);
            acc += wq4[0]*tv[0] + wq4[1]*tv[1] + wq4[2]*tv[2] + wq4[3]*tv[3];
        }
        __syncthreads();
        arena[ps][64 + po] = prelu_f(acc, pa);
    }
    __syncthreads();

    // u = W_kernel @ Q -> arena[ps][192+po]
    {
        float acc = 0.f;
        #pragma unroll
        for (int d4 = 0; d4 < 32; d4++) {
            f32x4 qv = *reinterpret_cast<const f32x4*>(&arena[ps][64 + d4 * 4]);
            f32x4 wk4 = *reinterpret_cast<const f32x4*>(Wker + (size_t)po * AA + d4 * 4);
            acc += wk4[0]*qv[0] + wk4[1]*qv[1] + wk4[2]*qv[2] + wk4[3]*qv[3];
        }
        arena[ps][192 + po] = acc;
    }
    __syncthreads();
    const float uw0 = arena[0][192 + 16 * w + c];
    const float uw1 = arena[1][192 + 16 * w + c];
    const float uw2 = arena[2][192 + 16 * w + c];
    const float uw3 = arena[3][192 + 16 * w + c];

    // ---- stage tile 0 for all 4 streams (A/B register sets)
    f32x4 stAlo, stAhi, stBlo, stBhi;
    ISSUE_R(0, 0, stAlo, stAhi); ISSUE_R(0, 1, stBlo, stBhi);
    STAGE_R(0, 0, stAlo, stAhi); STAGE_R(0, 1, stBlo, stBhi);
    ISSUE_R(0, 2, stAlo, stAhi); ISSUE_R(0, 3, stBlo, stBhi);
    STAGE_R(0, 2, stAlo, stAhi); STAGE_R(0, 3, stBlo, stBhi);
    __syncthreads();

    // ---- main loop: 1 barrier/tile; fused compute, shared weight loads
    float m0 = -INFINITY, l0 = 0.f, oacc0 = 0.f;
    float m1 = -INFINITY, l1 = 0.f, oacc1 = 0.f;
    float m2 = -INFINITY, l2 = 0.f, oacc2 = 0.f;
    float m3 = -INFINITY, l3 = 0.f, oacc3 = 0.f;
    f32x4 aVp0 = {0.f,0.f,0.f,0.f}, aVp1 = {0.f,0.f,0.f,0.f};
    f32x4 aVp2 = {0.f,0.f,0.f,0.f}, aVp3 = {0.f,0.f,0.f,0.f};

    for (int t = 0; t < NTIL; t++) {
        const int more = (t + 1 < NTIL);

        // issue next-tile loads for streams 0,1 (staged after first half-compute)
        if (more) { ISSUE_R(t + 1, 0, stAlo, stAhi); ISSUE_R(t + 1, 1, stBlo, stBhi); }

        // deferred softmax+fold of tile t-1 consumes aVp; then reuse as V accum
        if (t > 0) { SMFOLD(t - 1, 0); SMFOLD(t - 1, 1); SMFOLD(t - 1, 2); SMFOLD(t - 1, 3); }
        aVp0 = (f32x4){0.f,0.f,0.f,0.f}; aVp1 = (f32x4){0.f,0.f,0.f,0.f};
        aVp2 = (f32x4){0.f,0.f,0.f,0.f}; aVp3 = (f32x4){0.f,0.f,0.f,0.f};

        const char* rb0 = xbase + 0 * 16384 + (t & 1) * 8192 + c * 512;
        const char* rb1 = xbase + 1 * 16384 + (t & 1) * 8192 + c * 512;
        const char* rb2 = xbase + 2 * 16384 + (t & 1) * 8192 + c * 512;
        const char* rb3 = xbase + 3 * 16384 + (t & 1) * 8192 + c * 512;
        f32x4 aK0 = {0.f,0.f,0.f,0.f}, aK1 = {0.f,0.f,0.f,0.f};
        f32x4 aK2 = {0.f,0.f,0.f,0.f}, aK3 = {0.f,0.f,0.f,0.f};

        CHALF(0);

        if (more) {
            STAGE_R(t + 1, 0, stAlo, stAhi); ISSUE_R(t + 1, 2, stAlo, stAhi);
            STAGE_R(t + 1, 1, stBlo, stBhi); ISSUE_R(t + 1, 3, stBlo, stBhi);
        }

        CHALF(4);

        SCOREPART(t, 0); SCOREPART(t, 1); SCOREPART(t, 2); SCOREPART(t, 3);

        if (more) { STAGE_R(t + 1, 2, stAlo, stAhi); STAGE_R(t + 1, 3, stBlo, stBhi); }
        __syncthreads();
    }

    // ---- epilogue: fold last tile (sp published by final barrier)
    SMFOLD(NTIL - 1, 0); SMFOLD(NTIL - 1, 1);
    SMFOLD(NTIL - 1, 2); SMFOLD(NTIL - 1, 3);

    oacc0 += __shfl_xor(oacc0, 16, 64); oacc0 += __shfl_xor(oacc0, 32, 64);
    oacc1 += __shfl_xor(oacc1, 16, 64); oacc1 += __shfl_xor(oacc1, 32, 64);
    oacc2 += __shfl_xor(oacc2, 16, 64); oacc2 += __shfl_xor(oacc2, 32, 64);
    oacc3 += __shfl_xor(oacc3, 16, 64); oacc3 += __shfl_xor(oacc3, 32, 64);
    const float invl0 = 1.0f / l0, invl1 = 1.0f / l1;
    const float invl2 = 1.0f / l2, invl3 = 1.0f / l3;
    if (lane < 16) {
        arena[0][208 + 16 * w + lane] = oacc0 * invl0;
        arena[1][208 + 16 * w + lane] = oacc1 * invl1;
        arena[2][208 + 16 * w + lane] = oacc2 * invl2;
        arena[3][208 + 16 * w + lane] = oacc3 * invl3;
    }
    __syncthreads();

    // attn outputs (m/l/invl are block-uniform)
    if (tid < SS) {
        out[(size_t)NB * DSEQ + (size_t)(b0 + 0) * SS + tid] = __expf(arena[0][tid] - m0) * invl0;
        out[(size_t)NB * DSEQ + (size_t)(b0 + 1) * SS + tid] = __expf(arena[1][tid] - m1) * invl1;
        out[(size_t)NB * DSEQ + (size_t)(b0 + 2) * SS + tid] = __expf(arena[2][tid] - m2) * invl2;
        out[(size_t)NB * DSEQ + (size_t)(b0 + 3) * SS + tid] = __expf(arena[3][tid] - m3) * invl3;
    }

    // FFN: thread handles output o for streams sA and sA+2 (ffnW row read once)
    {
        const int o  = tid & 255;
        const int sA = tid >> 8;       // 0 or 1
        float accA = ffnb[o], accB = accA;
        #pragma unroll 8
        for (int a4 = 0; a4 < 32; a4++) {
            f32x4 wv4 = *reinterpret_cast<const f32x4*>(ffnW + (size_t)o * AA + a4 * 4);
            f32x4 ovA = *reinterpret_cast<const f32x4*>(&arena[sA][208 + a4 * 4]);
            f32x4 ovB = *reinterpret_cast<const f32x4*>(&arena[sA + 2][208 + a4 * 4]);
            accA += wv4[0]*ovA[0] + wv4[1]*ovA[1] + wv4[2]*ovA[2] + wv4[3]*ovA[3];
            accB += wv4[0]*ovB[0] + wv4[1]*ovB[1] + wv4[2]*ovB[2] + wv4[3]*ovB[3];
        }
        out[(size_t)(b0 + sA) * DSEQ + o]     = prelu_f(accA, pa);
        out[(size_t)(b0 + sA + 2) * DSEQ + o] = prelu_f(accB, pa);
    }
}

extern "C" void kernel_launch(void* const* d_in, const int* in_sizes, int n_in,
                              void* d_out, int out_size, void* d_ws, size_t ws_size,
                              hipStream_t stream) {
    const float* X    = (const float*)d_in[0];
    const int*   mask = (const int*)  d_in[1];
    const float* temb = (const float*)d_in[2];
    const float* Wq   = (const float*)d_in[3];
    const float* Wk   = (const float*)d_in[4];
    const float* Wv   = (const float*)d_in[5];
    const float* Wker = (const float*)d_in[6];
    const float* ffnW = (const float*)d_in[7];
    const float* ffnb = (const float*)d_in[8];
    const float* pa   = (const float*)d_in[9];
    float* out = (float*)d_out;

    __hip_bfloat16* Wb = (__hip_bfloat16*)d_ws;

    prep_kernel<<<256, 256, 0, stream>>>(Wk, Wv, Wb);
    pool_main<<<NB / NS, 512, 0, stream>>>(X, mask, temb, Wq, Wker, ffnW, ffnb, pa, Wb, out);
}